// Round 2
// baseline (235.475 us; speedup 1.0000x reference)
//
#include <hip/hip_runtime.h>

// ---------- types ----------
typedef __attribute__((ext_vector_type(8))) __bf16 bf16x8;
typedef __attribute__((ext_vector_type(4))) float  f32x4;

__device__ __forceinline__ unsigned short f2bf(float f) {
    unsigned int u = __builtin_bit_cast(unsigned int, f);
    u += 0x7fffu + ((u >> 16) & 1u);          // RNE
    return (unsigned short)(u >> 16);
}
__device__ __forceinline__ unsigned int pack2(float a, float b) {
    return (unsigned int)f2bf(a) | ((unsigned int)f2bf(b) << 16);
}

// swizzled element offset for a [64-row][64-elem bf16] LDS tile (128B rows).
// 16B chunks XOR-permuted by row to kill the 16-way bank conflict on
// ds_read_b128 column reads (G4: byte ^= (row&7)<<4).
__device__ __forceinline__ int swz8(int row, int chunk) {
    return row * 64 + ((chunk ^ (row & 7)) << 3);
}

__device__ __forceinline__ bf16x8 fragld(const unsigned short* lds, int row, int kk, int lane) {
    return *(const bf16x8*)(lds + swz8(row, kk * 4 + (lane >> 4)));
}

// ---------- staging helpers (tile = 64 rows x 64 k, 256 threads) ----------
// direct: global f32 [rows][K] K-contig -> LDS bf16 swizzled
__device__ __forceinline__ void stage_direct_f32(unsigned short* lds, const float* g,
                                                 int ldg, int tid) {
#pragma unroll
    for (int s = 0; s < 2; ++s) {
        int idx = tid + s * 256;
        int row = idx >> 3, c = idx & 7;
        const float* gp = g + (size_t)row * ldg + c * 8;
        float4 v0 = *(const float4*)gp;
        float4 v1 = *(const float4*)(gp + 4);
        uint4 wr4;
        wr4.x = pack2(v0.x, v0.y); wr4.y = pack2(v0.z, v0.w);
        wr4.z = pack2(v1.x, v1.y); wr4.w = pack2(v1.z, v1.w);
        *(uint4*)(lds + swz8(row, c)) = wr4;
    }
}
// direct: global bf16 [rows][K] K-contig -> LDS swizzled
__device__ __forceinline__ void stage_direct_bf16(unsigned short* lds, const unsigned short* g,
                                                  int ldg, int tid) {
#pragma unroll
    for (int s = 0; s < 2; ++s) {
        int idx = tid + s * 256;
        int row = idx >> 3, c = idx & 7;
        uint4 v = *(const uint4*)(g + (size_t)row * ldg + c * 8);
        *(uint4*)(lds + swz8(row, c)) = v;
    }
}
// transpose: global f32 [K][N] N-contig -> LDS rows=N, k-contig, swizzled
__device__ __forceinline__ void stage_trans_f32(unsigned short* lds, const float* g,
                                                int ldg, int tid) {
    int tk = (tid >> 4) * 4;
    int tn = (tid & 15) * 4;
    float rr[4][4];
#pragma unroll
    for (int i = 0; i < 4; ++i) {
        float4 v = *(const float4*)(g + (size_t)(tk + i) * ldg + tn);
        rr[i][0] = v.x; rr[i][1] = v.y; rr[i][2] = v.z; rr[i][3] = v.w;
    }
#pragma unroll
    for (int j = 0; j < 4; ++j) {
        int row = tn + j;
        uint2 w2;
        w2.x = pack2(rr[0][j], rr[1][j]);
        w2.y = pack2(rr[2][j], rr[3][j]);
        int off = row * 64 + (((tk >> 3) ^ (row & 7)) << 3) + (tk & 7);
        *(uint2*)(lds + off) = w2;
    }
}
// transpose: global bf16 [K][N] N-contig -> LDS rows=N, k-contig, swizzled
__device__ __forceinline__ void stage_trans_bf16(unsigned short* lds, const unsigned short* g,
                                                 int ldg, int tid) {
    int tk = (tid >> 4) * 4;
    int tn = (tid & 15) * 4;
    unsigned short rr[4][4];
#pragma unroll
    for (int i = 0; i < 4; ++i) {
        ushort4 v = *(const ushort4*)(g + (size_t)(tk + i) * ldg + tn);
        rr[i][0] = v.x; rr[i][1] = v.y; rr[i][2] = v.z; rr[i][3] = v.w;
    }
#pragma unroll
    for (int j = 0; j < 4; ++j) {
        int row = tn + j;
        ushort4 w4;
        w4.x = rr[0][j]; w4.y = rr[1][j]; w4.z = rr[2][j]; w4.w = rr[3][j];
        int off = row * 64 + (((tk >> 3) ^ (row & 7)) << 3) + (tk & 7);
        *(ushort4*)(lds + off) = w4;
    }
}

#define MFMA_STEP(As, Bs)                                                        \
    _Pragma("unroll")                                                            \
    for (int kk = 0; kk < 2; ++kk) {                                             \
        bf16x8 a0 = fragld(As, r0w + (lane & 15), kk, lane);                     \
        bf16x8 a1 = fragld(As, r0w + 16 + (lane & 15), kk, lane);                \
        bf16x8 b0 = fragld(Bs, c0w + (lane & 15), kk, lane);                     \
        bf16x8 b1 = fragld(Bs, c0w + 16 + (lane & 15), kk, lane);                \
        acc[0][0] = __builtin_amdgcn_mfma_f32_16x16x32_bf16(a0, b0, acc[0][0], 0, 0, 0); \
        acc[0][1] = __builtin_amdgcn_mfma_f32_16x16x32_bf16(a0, b1, acc[0][1], 0, 0, 0); \
        acc[1][0] = __builtin_amdgcn_mfma_f32_16x16x32_bf16(a1, b0, acc[1][0], 0, 0, 0); \
        acc[1][1] = __builtin_amdgcn_mfma_f32_16x16x32_bf16(a1, b1, acc[1][1], 0, 0, 0); \
    }

// ---------- kernel 1/2: K,V projection  C[bl,o] = X[bl,:]·W[o,:] + b ----------
// store bf16 as [b][n][l][64]
__global__ __launch_bounds__(256) void k_proj_kv(const float* __restrict__ X,
                                                 const float* __restrict__ W,
                                                 const float* __restrict__ bias,
                                                 unsigned short* __restrict__ out) {
    __shared__ alignas(16) unsigned short As[64 * 64];
    __shared__ alignas(16) unsigned short Bs[64 * 64];
    int tid = threadIdx.x, lane = tid & 63, wid = tid >> 6;
    int r0w = (wid >> 1) * 32, c0w = (wid & 1) * 32;
    int m0 = blockIdx.x * 64, n0 = blockIdx.y * 64;
    f32x4 acc[2][2] = {};
    for (int kt = 0; kt < 512; kt += 64) {
        stage_direct_f32(As, X + (size_t)m0 * 512 + kt, 512, tid);
        stage_direct_f32(Bs, W + (size_t)n0 * 512 + kt, 512, tid);
        __syncthreads();
        MFMA_STEP(As, Bs)
        __syncthreads();
    }
#pragma unroll
    for (int j = 0; j < 2; ++j) {
        int o = n0 + c0w + j * 16 + (lane & 15);
        float bb = bias[o];
        int n = o >> 6, d = o & 63;
#pragma unroll
        for (int i = 0; i < 2; ++i) {
#pragma unroll
            for (int reg = 0; reg < 4; ++reg) {
                int r = m0 + r0w + i * 16 + ((lane >> 4) << 2) + reg;
                int b = r >> 10, l = r & 1023;
                out[(((size_t)(b * 8 + n)) * 1024 + l) * 64 + d] = f2bf(acc[i][j][reg] + bb);
            }
        }
    }
}

// ---------- kernel 3: Q projection (tn)  C[p,o] = sum_c q[b,c,p]·Wq[o,c] + bq, x 1/8 ----------
__global__ __launch_bounds__(256) void k_proj_q(const float* __restrict__ Q,
                                                const float* __restrict__ Wq,
                                                const float* __restrict__ bq,
                                                unsigned short* __restrict__ qh) {
    __shared__ alignas(16) unsigned short As[64 * 64];
    __shared__ alignas(16) unsigned short Bs[64 * 64];
    int tid = threadIdx.x, lane = tid & 63, wid = tid >> 6;
    int r0w = (wid >> 1) * 32, c0w = (wid & 1) * 32;
    int b = blockIdx.z;
    int m0 = blockIdx.x * 64;  // p rows
    int n0 = blockIdx.y * 64;  // o cols
    const float* Qb = Q + (size_t)b * 512 * 1024;
    f32x4 acc[2][2] = {};
    for (int kt = 0; kt < 512; kt += 64) {
        stage_trans_f32(As, Qb + (size_t)kt * 1024 + m0, 1024, tid);
        stage_direct_f32(Bs, Wq + (size_t)n0 * 512 + kt, 512, tid);
        __syncthreads();
        MFMA_STEP(As, Bs)
        __syncthreads();
    }
#pragma unroll
    for (int j = 0; j < 2; ++j) {
        int o = n0 + c0w + j * 16 + (lane & 15);
        float bb = bq[o];
        int n = o >> 6, d = o & 63;
#pragma unroll
        for (int i = 0; i < 2; ++i) {
#pragma unroll
            for (int reg = 0; reg < 4; ++reg) {
                int p = m0 + r0w + i * 16 + ((lane >> 4) << 2) + reg;
                qh[(((size_t)(b * 8 + n)) * 1024 + p) * 64 + d] =
                    f2bf((acc[i][j][reg] + bb) * 0.125f);  // fold 1/sqrt(64), exact
            }
        }
    }
}

// ---------- kernel 4: flash attention ----------
// per block: one (b,n), 64 q-rows. K/V tiles of 64 in LDS, online softmax.
// mask arrives as int32 (JAX bool -> int32 on device).
__global__ __launch_bounds__(256) void k_attn(const unsigned short* __restrict__ qh,
                                              const unsigned short* __restrict__ kh,
                                              const unsigned short* __restrict__ vh,
                                              const int* __restrict__ mask,
                                              unsigned short* __restrict__ attn) {
    __shared__ alignas(16) unsigned short Qs[64 * 64];
    __shared__ alignas(16) unsigned short Ks[64 * 64];
    __shared__ alignas(16) unsigned short Vs[64 * 64];   // transposed: [d][l]
    __shared__ alignas(16) unsigned short Ps[4][16 * 64];
    int tid = threadIdx.x, lane = tid & 63, wv = tid >> 6;
    int bn = blockIdx.x;
    int b = bn >> 3, n = bn & 7;
    int p0 = blockIdx.y * 64;
    const unsigned short* qbase = qh + (((size_t)bn) * 1024 + p0) * 64;
    const unsigned short* kbase = kh + ((size_t)bn) * 1024 * 64;
    const unsigned short* vbase = vh + ((size_t)bn) * 1024 * 64;
    const int* mbase = mask + (size_t)b * 1024;

    stage_direct_bf16(Qs, qbase, 64, tid);
    __syncthreads();
    bf16x8 aq0 = fragld(Qs, wv * 16 + (lane & 15), 0, lane);
    bf16x8 aq1 = fragld(Qs, wv * 16 + (lane & 15), 1, lane);

    float mrow[4], lrow[4];
    f32x4 o4[4] = {};
#pragma unroll
    for (int r = 0; r < 4; ++r) { mrow[r] = -3e38f; lrow[r] = 0.f; }

    for (int t = 0; t < 16; ++t) {
        int l0 = t * 64;
        __syncthreads();  // previous iter's readers done before restage
        stage_direct_bf16(Ks, kbase + (size_t)l0 * 64, 64, tid);
        stage_trans_bf16(Vs, vbase + (size_t)l0 * 64, 64, tid);
        __syncthreads();

        // S = Q·K^T (Q pre-scaled by 1/8)
        f32x4 s[4] = {};
#pragma unroll
        for (int j = 0; j < 4; ++j) {
            bf16x8 bk0 = fragld(Ks, j * 16 + (lane & 15), 0, lane);
            bf16x8 bk1 = fragld(Ks, j * 16 + (lane & 15), 1, lane);
            s[j] = __builtin_amdgcn_mfma_f32_16x16x32_bf16(aq0, bk0, s[j], 0, 0, 0);
            s[j] = __builtin_amdgcn_mfma_f32_16x16x32_bf16(aq1, bk1, s[j], 0, 0, 0);
        }
        // mask (per column); reference: where(mask) -> NEG_INF
#pragma unroll
        for (int j = 0; j < 4; ++j) {
            if (mbase[l0 + j * 16 + (lane & 15)] != 0) {
#pragma unroll
                for (int reg = 0; reg < 4; ++reg) s[j][reg] = -1e9f;
            }
        }
        // online softmax; rows of this lane: (lane>>4)*4 + reg, shared by 16-lane group
        float pv[4][4], corr[4];
#pragma unroll
        for (int reg = 0; reg < 4; ++reg) {
            float mx = fmaxf(fmaxf(s[0][reg], s[1][reg]), fmaxf(s[2][reg], s[3][reg]));
#pragma unroll
            for (int off = 1; off < 16; off <<= 1) mx = fmaxf(mx, __shfl_xor(mx, off, 64));
            float mnew = fmaxf(mrow[reg], mx);
            corr[reg] = __expf(mrow[reg] - mnew);
            mrow[reg] = mnew;
            float sum = 0.f;
#pragma unroll
            for (int j = 0; j < 4; ++j) {
                float p = __expf(s[j][reg] - mnew);
                pv[j][reg] = p;
                sum += p;
            }
#pragma unroll
            for (int off = 1; off < 16; off <<= 1) sum += __shfl_xor(sum, off, 64);
            lrow[reg] = lrow[reg] * corr[reg] + sum;
        }
        // P -> per-wave LDS (swizzled), rescale O, then O += P·V
        unsigned short* Pw = Ps[wv];
#pragma unroll
        for (int j = 0; j < 4; ++j) {
            int c = j * 16 + (lane & 15);
#pragma unroll
            for (int reg = 0; reg < 4; ++reg) {
                int pr = ((lane >> 4) << 2) + reg;
                Pw[pr * 64 + (((c >> 3) ^ (pr & 7)) << 3) + (c & 7)] = f2bf(pv[j][reg]);
            }
        }
#pragma unroll
        for (int jd = 0; jd < 4; ++jd)
#pragma unroll
            for (int reg = 0; reg < 4; ++reg) o4[jd][reg] *= corr[reg];
#pragma unroll
        for (int kk = 0; kk < 2; ++kk) {
            bf16x8 ap = fragld(Pw, (lane & 15), kk, lane);
#pragma unroll
            for (int jd = 0; jd < 4; ++jd) {
                bf16x8 bv = fragld(Vs, jd * 16 + (lane & 15), kk, lane);
                o4[jd] = __builtin_amdgcn_mfma_f32_16x16x32_bf16(ap, bv, o4[jd], 0, 0, 0);
            }
        }
    }
    // epilogue: normalize, transpose via per-wave LDS, store [c][p] 32B-coalesced
    float inv[4];
#pragma unroll
    for (int reg = 0; reg < 4; ++reg) inv[reg] = 1.f / lrow[reg];
    unsigned short* Ow = Ps[wv];  // reuse: [64 d][16 p]
#pragma unroll
    for (int jd = 0; jd < 4; ++jd) {
        int d = jd * 16 + (lane & 15);
#pragma unroll
        for (int reg = 0; reg < 4; ++reg) {
            int pr = ((lane >> 4) << 2) + reg;
            Ow[d * 16 + pr] = f2bf(o4[jd][reg] * inv[reg]);
        }
    }
    int d = lane;
    uint4 w0 = *(const uint4*)(Ow + d * 16);
    uint4 w1 = *(const uint4*)(Ow + d * 16 + 8);
    size_t oaddr = ((size_t)(b * 512 + n * 64 + d)) * 1024 + p0 + wv * 16;
    *(uint4*)(attn + oaddr) = w0;
    *(uint4*)(attn + oaddr + 8) = w1;
}

// ---------- kernel 5: final 1x1 conv (nn) + bias + relu ----------
// C[o,p] = relu(sum_c Wm[o,c]·attn[b,c,p] + bm[o]) -> out[b][o][p] f32
__global__ __launch_bounds__(256) void k_final(const unsigned short* __restrict__ attn,
                                               const float* __restrict__ Wm,
                                               const float* __restrict__ bm,
                                               float* __restrict__ out) {
    __shared__ alignas(16) unsigned short As[64 * 64];
    __shared__ alignas(16) unsigned short Bs[64 * 64];
    int tid = threadIdx.x, lane = tid & 63, wid = tid >> 6;
    int r0w = (wid >> 1) * 32, c0w = (wid & 1) * 32;
    int b = blockIdx.z;
    int m0 = blockIdx.x * 64;  // o rows
    int n0 = blockIdx.y * 64;  // p cols
    const unsigned short* Ab = attn + (size_t)b * 512 * 1024;
    f32x4 acc[2][2] = {};
    for (int kt = 0; kt < 512; kt += 64) {
        stage_direct_f32(As, Wm + (size_t)m0 * 512 + kt, 512, tid);
        stage_trans_bf16(Bs, Ab + (size_t)kt * 1024 + n0, 1024, tid);
        __syncthreads();
        MFMA_STEP(As, Bs)
        __syncthreads();
    }
#pragma unroll
    for (int i = 0; i < 2; ++i) {
#pragma unroll
        for (int reg = 0; reg < 4; ++reg) {
            int o = m0 + r0w + i * 16 + ((lane >> 4) << 2) + reg;
            float bb = bm[o];
#pragma unroll
            for (int j = 0; j < 2; ++j) {
                int p = n0 + c0w + j * 16 + (lane & 15);
                out[((size_t)(b * 512 + o)) * 1024 + p] = fmaxf(acc[i][j][reg] + bb, 0.f);
            }
        }
    }
}

extern "C" void kernel_launch(void* const* d_in, const int* in_sizes, int n_in,
                              void* d_out, int out_size, void* d_ws, size_t ws_size,
                              hipStream_t stream) {
    const float* v  = (const float*)d_in[0];
    const float* k  = (const float*)d_in[1];
    const float* q  = (const float*)d_in[2];
    const int*   mask = (const int*)d_in[3];   // JAX bool -> int32
    const float* Wv = (const float*)d_in[4];
    const float* bv = (const float*)d_in[5];
    const float* Wk = (const float*)d_in[6];
    const float* bk = (const float*)d_in[7];
    const float* Wq = (const float*)d_in[8];
    const float* bq = (const float*)d_in[9];
    const float* Wm = (const float*)d_in[10];
    const float* bm = (const float*)d_in[11];
    float* out = (float*)d_out;

    const size_t E = (size_t)8 * 8 * 1024 * 64;  // 4M bf16 elems = 8MB each
    unsigned short* kh   = (unsigned short*)d_ws;
    unsigned short* vh   = kh + E;
    unsigned short* qh   = vh + E;
    unsigned short* attn = qh + E;

    dim3 blk(256);
    k_proj_kv<<<dim3(128, 8), blk, 0, stream>>>(k, Wk, bk, kh);
    k_proj_kv<<<dim3(128, 8), blk, 0, stream>>>(v, Wv, bv, vh);
    k_proj_q <<<dim3(16, 8, 8), blk, 0, stream>>>(q, Wq, bq, qh);
    k_attn   <<<dim3(64, 16), blk, 0, stream>>>(qh, kh, vh, mask, attn);
    k_final  <<<dim3(8, 16, 8), blk, 0, stream>>>(attn, Wm, bm, out);
}